// Round 17
// baseline (252.103 us; speedup 1.0000x reference)
//
#include <hip/hip_runtime.h>
#include <hip/hip_bf16.h>
#include <cstdint>
#include <cstddef>

#define B_SZ   2
#define T_SEQ  2048
#define C_DIM  2048
#define NH     16
#define HD     128

typedef __attribute__((ext_vector_type(8))) short s8v;      // 8 bf16
typedef __attribute__((ext_vector_type(4))) float f32x4;

typedef __attribute__((address_space(3))) char lds_char;
typedef __attribute__((address_space(1))) const char glob_char;

// softmax runs in exp2 domain: q pre-scale folds 1/sqrt(HD) * log2(e)
#define QSCALE 0.12751887f   // 0.088388348 * 1.4426950

__device__ __forceinline__ unsigned short f2bf(float f) {
    union { float f; uint32_t i; } v; v.f = f;
    uint32_t r = (v.i + 0x7FFFu + ((v.i >> 16) & 1u)) >> 16;
    return (unsigned short)r;
}

// packed pair: lo = bf16(a), hi = bf16(b)
__device__ __forceinline__ unsigned int cvt2_bf16(float a, float b) {
    unsigned int w;
    asm("v_cvt_pk_bf16_f32 %0, %1, %2" : "=v"(w) : "v"(a), "v"(b));
    return w;
}

// -------------------------------------------------------------- fused prep
__global__ __launch_bounds__(256) void k_prep(
        const float* __restrict__ x, unsigned short* __restrict__ xb,
        float* __restrict__ cosT, float* __restrict__ sinT,
        float* __restrict__ cosT2, float* __restrict__ sinT2,
        const float* __restrict__ wq, const float* __restrict__ wk,
        const float* __restrict__ wv, const float* __restrict__ wo,
        unsigned short* __restrict__ wT, unsigned short* __restrict__ woT) {
    __shared__ unsigned short tile[64][66];
    int blk = blockIdx.x;
    int tid = threadIdx.x;

    if (blk < 2048) {
        int i = blk * 256 + tid;
        const int n4 = 4096 * 2048 / 4;
        const int stride = 2048 * 256;
        for (; i < n4; i += stride) {
            float4 v = reinterpret_cast<const float4*>(x)[i];
            ushort4 o;
            o.x = f2bf(v.x); o.y = f2bf(v.y); o.z = f2bf(v.z); o.w = f2bf(v.w);
            reinterpret_cast<ushort4*>(xb)[i] = o;
        }
        return;
    }
    blk -= 2048;
    if (blk < 512) {
        int idx = blk * 256 + tid;            // T*64
        int t = idx >> 6, i = idx & 63;
        float inv = powf(10000.0f, -(float)i / 64.0f);
        float ang = (float)t * inv;
        float c = cosf(ang), s = sinf(ang);
        cosT[idx] = c;  sinT[idx] = s;
        cosT2[i * T_SEQ + t] = c;  sinT2[i * T_SEQ + t] = s;
        return;
    }
    blk -= 512;

    const float* in; unsigned short* out; int C, ldo, bx, by;
    if (blk < 1024) {
        in = wq; out = wT; C = 2048; ldo = 2048;
        bx = blk & 31; by = blk >> 5;
    } else if (blk < 1088) {
        int l = blk - 1024;
        in = wk; out = wT + (size_t)2048 * 2048; C = 128; ldo = 2048;
        bx = l & 1; by = l >> 1;
    } else if (blk < 1152) {
        int l = blk - 1088;
        in = wv; out = wT + (size_t)2176 * 2048; C = 128; ldo = 2048;
        bx = l & 1; by = l >> 1;
    } else {
        int l = blk - 1152;
        in = wo; out = woT; C = 2048; ldo = 2048;
        bx = l & 31; by = l >> 5;
    }
    int x0 = bx * 64, y0 = by * 64;
    int tx = tid & 63, ty = tid >> 6;
#pragma unroll
    for (int j = 0; j < 16; ++j) {
        int r = y0 + ty + j * 4;
        tile[ty + j * 4][tx] = f2bf(in[(size_t)r * C + x0 + tx]);
    }
    __syncthreads();
#pragma unroll
    for (int j = 0; j < 16; ++j) {
        int orow = x0 + ty + j * 4;
        out[(size_t)orow * ldo + y0 + tx] = tile[tx][ty + j * 4];
    }
}

// ----------------------------------------------------------------- GEMM (BT)
#define BM 128
#define BN 128
#define BK 64

__global__ __launch_bounds__(256) void k_gemm_bt(
        const unsigned short* __restrict__ A,
        const unsigned short* __restrict__ Bt,
        float* __restrict__ C, int M, int N, int K, int ldc, int gx) {
    __shared__ char smem[BM * BK * 2 + BN * BK * 2];   // 16KB A + 16KB B
    char* As = smem;
    char* Bs = smem + BM * BK * 2;
    int tid = threadIdx.x, lane = tid & 63, wid = tid >> 6;
    int nwg = gridDim.x, cpx = nwg >> 3;
    int orig = blockIdx.x;
    int wg = (orig & 7) * cpx + (orig >> 3);   // bijective: nwg % 8 == 0
    int bx = wg % gx, by = wg / gx;
    int m0 = by * BM, n0 = bx * BN;
    int wr = wid >> 1, wc = wid & 1;

    f32x4 acc[4][4] = {};

    int srow = wid * 32 + (lane >> 3);
    int cp = lane & 7;

    for (int k0 = 0; k0 < K; k0 += BK) {
#pragma unroll
        for (int i = 0; i < 4; ++i) {
            int row = srow + i * 8;
            int c = cp ^ (row & 7);
            const unsigned short* ga = A + (size_t)(m0 + row) * K + k0 + c * 8;
            const unsigned short* gb = Bt + (size_t)(n0 + row) * K + k0 + c * 8;
            __builtin_amdgcn_global_load_lds((glob_char*)ga,
                (lds_char*)(As + wid * 4096 + i * 1024), 16, 0, 0);
            __builtin_amdgcn_global_load_lds((glob_char*)gb,
                (lds_char*)(Bs + wid * 4096 + i * 1024), 16, 0, 0);
        }
        __syncthreads();

#pragma unroll
        for (int kc = 0; kc < 2; ++kc) {
            s8v af[4], bfr[4];
#pragma unroll
            for (int mi = 0; mi < 4; ++mi) {
                int row = wr * 64 + mi * 16 + (lane & 15);
                int slot = (kc * 4 + (lane >> 4)) ^ (row & 7);
                af[mi] = *reinterpret_cast<const s8v*>(As + row * 128 + slot * 16);
            }
#pragma unroll
            for (int ni = 0; ni < 4; ++ni) {
                int row = wc * 64 + ni * 16 + (lane & 15);
                int slot = (kc * 4 + (lane >> 4)) ^ (row & 7);
                bfr[ni] = *reinterpret_cast<const s8v*>(Bs + row * 128 + slot * 16);
            }
#pragma unroll
            for (int mi = 0; mi < 4; ++mi)
#pragma unroll
                for (int ni = 0; ni < 4; ++ni)
                    acc[mi][ni] = __builtin_amdgcn_mfma_f32_16x16x32_bf16(
                        af[mi], bfr[ni], acc[mi][ni], 0, 0, 0);
        }
        __syncthreads();
    }

#pragma unroll
    for (int mi = 0; mi < 4; ++mi) {
        int row = m0 + wr * 64 + mi * 16 + ((lane >> 4) << 2);
#pragma unroll
        for (int ni = 0; ni < 4; ++ni) {
            int col = n0 + wc * 64 + ni * 16 + (lane & 15);
            float* cp2 = C + (size_t)row * ldc + col;
#pragma unroll
            for (int r = 0; r < 4; ++r)
                cp2[(size_t)r * ldc] = acc[mi][ni][r];
        }
    }
}

// ------------------------- QKV GEMM, 2x2 wave split + LDS RoPE exchange
__global__ __launch_bounds__(256) void k_gemm_qkv(
        const unsigned short* __restrict__ A,
        const unsigned short* __restrict__ Bt,
        const float* __restrict__ cosT2,
        const float* __restrict__ sinT2,
        unsigned short* __restrict__ qB,
        float* __restrict__ qkvKV) {
    const int GX = 18, K = 2048;
    __shared__ char smem[34816];   // 32KB staging; 34KB epilogue exchange
    char* As = smem;
    char* Bs = smem + BM * BK * 2;
    int tid = threadIdx.x, lane = tid & 63, wid = tid >> 6;
    int nwg = gridDim.x, cpx = nwg >> 3;       // 576 -> 72
    int orig = blockIdx.x;
    int wg = (orig & 7) * cpx + (orig >> 3);
    int bx = wg % GX, by = wg / GX;
    int m0 = by * BM, n0 = bx * BN;
    int l15 = lane & 15, l4 = lane >> 4;
    int wr = wid >> 1, wc = wid & 1;

    f32x4 acc[4][4] = {};

    int srow = wid * 32 + (lane >> 3);
    int cp = lane & 7;

    for (int k0 = 0; k0 < K; k0 += BK) {
#pragma unroll
        for (int i = 0; i < 4; ++i) {
            int row = srow + i * 8;
            int c = cp ^ (row & 7);
            const unsigned short* ga = A + (size_t)(m0 + row) * K + k0 + c * 8;
            const unsigned short* gb = Bt + (size_t)(n0 + row) * K + k0 + c * 8;
            __builtin_amdgcn_global_load_lds((glob_char*)ga,
                (lds_char*)(As + wid * 4096 + i * 1024), 16, 0, 0);
            __builtin_amdgcn_global_load_lds((glob_char*)gb,
                (lds_char*)(Bs + wid * 4096 + i * 1024), 16, 0, 0);
        }
        __syncthreads();

#pragma unroll
        for (int kc = 0; kc < 2; ++kc) {
            s8v af[4], bfr[4];
#pragma unroll
            for (int mi = 0; mi < 4; ++mi) {
                int row = wr * 64 + mi * 16 + l15;
                int slot = (kc * 4 + l4) ^ (row & 7);
                af[mi] = *reinterpret_cast<const s8v*>(As + row * 128 + slot * 16);
            }
#pragma unroll
            for (int ni = 0; ni < 4; ++ni) {
                int row = wc * 64 + ni * 16 + l15;
                int slot = (kc * 4 + l4) ^ (row & 7);
                bfr[ni] = *reinterpret_cast<const s8v*>(Bs + row * 128 + slot * 16);
            }
#pragma unroll
            for (int mi = 0; mi < 4; ++mi)
#pragma unroll
                for (int ni = 0; ni < 4; ++ni)
                    acc[mi][ni] = __builtin_amdgcn_mfma_f32_16x16x32_bf16(
                        af[mi], bfr[ni], acc[mi][ni], 0, 0, 0);
        }
        __syncthreads();
    }

    if (bx < 16) {
        // ---- RoPE epilogue with cross-wc LDS exchange
        float* xch = reinterpret_cast<float*>(smem);
        if (wc == 1) {
            float* base = xch + ((size_t)wr * 64 + lane) * 68;
#pragma unroll
            for (int mi = 0; mi < 4; ++mi)
#pragma unroll
                for (int ni = 0; ni < 4; ++ni)
                    *reinterpret_cast<f32x4*>(base + mi * 16 + ni * 4) =
                        acc[mi][ni];
        }
        __syncthreads();
        if (wc == 0) {
            int b = m0 >> 11, h = bx;
            const float* pbase = xch + ((size_t)wr * 64 + lane) * 68;
#pragma unroll
            for (int mi = 0; mi < 4; ++mi) {
                int t0 = ((m0 & (T_SEQ - 1)) + wr * 64 + mi * 16 + l4 * 4);
#pragma unroll
                for (int ni = 0; ni < 4; ++ni) {
                    int d = ni * 16 + l15;          // d in [0,64)
                    float4 c4 = *reinterpret_cast<const float4*>(
                        cosT2 + (size_t)d * T_SEQ + t0);
                    float4 s4 = *reinterpret_cast<const float4*>(
                        sinT2 + (size_t)d * T_SEQ + t0);
                    f32x4 px = *reinterpret_cast<const f32x4*>(
                        pbase + mi * 16 + ni * 4);
#pragma unroll
                    for (int r = 0; r < 4; ++r) {
                        float x1 = acc[mi][ni][r];
                        float x2 = px[r];
                        float cc = (&c4.x)[r], ss = (&s4.x)[r];
                        float o1 = (x1 * cc - x2 * ss) * QSCALE;
                        float o2 = (x2 * cc + x1 * ss) * QSCALE;
                        size_t qoff = ((size_t)(b * NH + h) * T_SEQ + t0 + r)
                                      * HD + 2 * d;
                        *reinterpret_cast<unsigned int*>(qB + qoff) =
                            cvt2_bf16(o1, o2);
                    }
                }
            }
        }
    } else {
        int colb = (bx - 16) * 128;
#pragma unroll
        for (int mi = 0; mi < 4; ++mi) {
            int row = m0 + wr * 64 + mi * 16 + l4 * 4;
#pragma unroll
            for (int ni = 0; ni < 4; ++ni) {
                int col = colb + wc * 64 + ni * 16 + l15;
                float* cp2 = qkvKV + (size_t)row * 256 + col;
#pragma unroll
                for (int r = 0; r < 4; ++r)
                    cp2[(size_t)r * 256] = acc[mi][ni][r];
            }
        }
    }
}

// -------------------------------------------- slim k/v transform + broadcast
__global__ __launch_bounds__(192) void k_kv_transform(
                               const float* __restrict__ qkvKV,
                               const float* __restrict__ cosT,
                               const float* __restrict__ sinT,
                               unsigned short* __restrict__ kB,
                               unsigned short* __restrict__ vT,
                               float* __restrict__ kexp,
                               float* __restrict__ vexp) {
    int bt = blockIdx.x;
    int b = bt >> 11, t = bt & 2047;
    int tid = threadIdx.x;
    const float* base = qkvKV + (size_t)bt * 256;

    if (tid < 64) {
        int d = tid;
        float c = cosT[t * 64 + d], s = sinT[t * 64 + d];
        float k1 = base[d], k2 = base[d + 64];
        float o1 = k1 * c - k2 * s;
        float o2 = k2 * c + k1 * s;
        size_t koff = ((size_t)b * T_SEQ + t) * HD + 2 * d;   // interleaved
        *reinterpret_cast<unsigned int*>(kB + koff) = cvt2_bf16(o1, o2);
#pragma unroll
        for (int h = 0; h < NH; ++h) {
            size_t eoff = ((size_t)(b * NH + h) * T_SEQ + t) * HD + d;
            kexp[eoff] = o1;          // canonical layout (required output)
            kexp[eoff + 64] = o2;
        }
    } else {
        int d = tid - 64;             // 0..127
        float v = base[128 + d];
        vT[((size_t)b * HD + d) * T_SEQ + t] = f2bf(v);
#pragma unroll
        for (int h = 0; h < NH; ++h)
            vexp[((size_t)(b * NH + h) * T_SEQ + t) * HD + d] = v;
    }
}

// ---------------------------------------------------------- flash attention
// v14: 2 HEADS PER WAVE (MQA head-sharing). Block = (b, u, head-pair hp);
// grid 512. K/V frag LDS reads shared across both heads; per-head QK MFMA,
// softmax, in-reg P-exchange, PV. Total tiles and staging HALVED vs v13;
// the 2 heads' independent chains give within-wave ILP to hide latency.
// Register audit: o[2][8]=64 + aq[2][4]=32 + transient sfr/P ~40 -> ~145
// VGPR < 168 cap @ (256,3). Spill gate: VGPR_Count / WRITE_SIZE.
__global__ __launch_bounds__(256, 3) void k_flash_attn(
        const unsigned short* __restrict__ qB,
        const unsigned short* __restrict__ kB,
        const unsigned short* __restrict__ vT,
        unsigned short* __restrict__ yattn) {
    __shared__ char smem[49152];   // 3 x (K 8K | V 8K)
    int tid = threadIdx.x, lane = tid & 63, wvid = tid >> 6;
    int l15 = lane & 15, l4 = lane >> 4;
    int blk = blockIdx.x;
    int bp = blk & 15;                 // (b, head-pair)
    int b = bp >> 3, hp = bp & 7;      // heads {2hp, 2hp+1}
    int g = blk >> 4;                  // 0..31  (u-unit group)
    int a = g & 7, qq = g >> 3;
    int u = (qq == 0) ? (31 - a) : (qq == 1) ? (16 + a)
          : (qq == 2) ? (15 - a) : a;          // CU-balanced, heavy first
    int qrow0 = u * 64 + wvid * 16;

    const unsigned short* kbB   = kB + (size_t)b * T_SEQ * HD;
    const unsigned short* vbase = vT + (size_t)b * HD * T_SEQ;

    // Q fragments for both heads (B-operand: col=q=l15, k-window phys)
    s8v aq[2][4];
#pragma unroll
    for (int hh = 0; hh < 2; ++hh) {
        const unsigned short* qbase =
            qB + ((size_t)(b * NH + 2 * hp + hh) * T_SEQ + qrow0) * HD;
#pragma unroll
        for (int kc = 0; kc < 4; ++kc)
            aq[hh][kc] = *reinterpret_cast<const s8v*>(
                qbase + (size_t)l15 * HD + kc * 32 + l4 * 8);
    }

    float m[2] = {-3e38f, -3e38f}, l[2] = {0.f, 0.f};
    f32x4 o[2][8] = {};   // per head O^T: col=q=l15, d = ds*16 + l4*4 + r

    int NT = 2 * u + 2;   // 32-wide kv tiles

    auto stage = [&](int buf, int t) {
        int kv0 = t * 32;
        char* kdst = smem + buf * 16384;
        char* vdst = smem + buf * 16384 + 8192;
#pragma unroll
        for (int j = 0; j < 2; ++j) {
            int n = j * 256 + tid;            // K chunk 0..511
            int row = n >> 4, ch = n & 15;
            const unsigned short* src =
                kbB + (size_t)(kv0 + row) * HD + (ch ^ (row & 7)) * 8;
            __builtin_amdgcn_global_load_lds((glob_char*)src,
                (lds_char*)(kdst + j * 4096 + wvid * 1024), 16, 0, 0);
        }
#pragma unroll
        for (int j = 0; j < 2; ++j) {
            int n = j * 256 + tid;            // V chunk 0..511
            int row = n >> 2, ch = n & 3;     // 4 chunks per 64B row
            const unsigned short* src =
                vbase + (size_t)row * T_SEQ + kv0 + (ch ^ ((row >> 1) & 3)) * 8;
            __builtin_amdgcn_global_load_lds((glob_char*)src,
                (lds_char*)(vdst + j * 4096 + wvid * 1024), 16, 0, 0);
        }
    };

    stage(0, 0);
    stage(1, 1);
    asm volatile("s_waitcnt vmcnt(4)" ::: "memory");
    __builtin_amdgcn_s_barrier();
    __builtin_amdgcn_sched_barrier(0);

    int cur = 0;
    for (int t = 0; t < NT; ++t) {
        int nb = cur + 2; if (nb >= 3) nb -= 3;
        if (t + 2 < NT) stage(nb, t + 2);     // 2-deep prefetch, issued first
        int kv0 = t * 32;
        const char* Kc = smem + cur * 16384;
        const char* Vc = smem + cur * 16384 + 8192;
        int act = (kv0 <= qrow0 + 15);

        if (act) {
            // ---- S^T = K Q^T for BOTH heads (K-frags shared)
            f32x4 sfr[2][2] = {};
            __builtin_amdgcn_s_setprio(1);
#pragma unroll
            for (int kc = 0; kc < 4; ++kc) {
                s8v kf[2];
#pragma unroll
                for (int n = 0; n < 2; ++n) {
                    int row = n * 16 + l15;
                    int byte = row * 256 +
                        ((kc * 64 + l4 * 16) ^ ((row & 7) << 4));
                    kf[n] = *reinterpret_cast<const s8v*>(Kc + byte);
                }
#pragma unroll
                for (int hh = 0; hh < 2; ++hh)
#pragma unroll
                    for (int n = 0; n < 2; ++n)
                        sfr[hh][n] = __builtin_amdgcn_mfma_f32_16x16x32_bf16(
                            kf[n], aq[hh][kc], sfr[hh][n], 0, 0, 0);
            }
            __builtin_amdgcn_s_setprio(0);

            // ---- per-head: mask, softmax, P-build, PV (V-frags shared)
            union { unsigned int u[4]; s8v v; } pf[2];
#pragma unroll
            for (int hh = 0; hh < 2; ++hh) {
                if (kv0 + 31 > qrow0) {
                    int qa = qrow0 + l15;
#pragma unroll
                    for (int n = 0; n < 2; ++n)
#pragma unroll
                        for (int r = 0; r < 4; ++r) {
                            int kv = kv0 + n * 16 + l4 * 4 + r;
                            if (kv > qa) sfr[hh][n][r] = -1e9f;
                        }
                }
                float pm = sfr[hh][0][0];
#pragma unroll
                for (int r = 1; r < 4; ++r) pm = fmaxf(pm, sfr[hh][0][r]);
#pragma unroll
                for (int r = 0; r < 4; ++r) pm = fmaxf(pm, sfr[hh][1][r]);
                pm = fmaxf(pm, __shfl_xor(pm, 16));
                pm = fmaxf(pm, __shfl_xor(pm, 32));
                if (!__all(pm <= m[hh] + 8.0f)) {   // defer-max (T13)
                    float mn = fmaxf(m[hh], pm);
                    float al = exp2f(m[hh] - mn);
                    l[hh] *= al;
#pragma unroll
                    for (int ds = 0; ds < 8; ++ds)
#pragma unroll
                        for (int r = 0; r < 4; ++r) o[hh][ds][r] *= al;
                    m[hh] = mn;
                }
#pragma unroll
                for (int n = 0; n < 2; ++n)
#pragma unroll
                    for (int r = 0; r < 4; ++r) {
                        float p = exp2f(sfr[hh][n][r] - m[hh]);
                        sfr[hh][n][r] = p;
                        l[hh] += p;
                    }

                unsigned int a0 = cvt2_bf16(sfr[hh][0][0], sfr[hh][0][1]);
                unsigned int a1 = cvt2_bf16(sfr[hh][0][2], sfr[hh][0][3]);
                unsigned int b0 = cvt2_bf16(sfr[hh][1][0], sfr[hh][1][1]);
                unsigned int b1 = cvt2_bf16(sfr[hh][1][2], sfr[hh][1][3]);
                int srcE = (lane & 15) | ((lane & 16) << 1);
                int srcO = srcE + 16;
                unsigned int ae0 = __shfl(a0, srcE), ae1 = __shfl(a1, srcE);
                unsigned int be0 = __shfl(b0, srcE), be1 = __shfl(b1, srcE);
                unsigned int ao0 = __shfl(a0, srcO), ao1 = __shfl(a1, srcO);
                unsigned int bo0 = __shfl(b0, srcO), bo1 = __shfl(b1, srcO);
                bool lo = (lane & 32) == 0;
                pf[hh].u[0] = lo ? ae0 : be0;
                pf[hh].u[1] = lo ? ae1 : be1;
                pf[hh].u[2] = lo ? ao0 : bo0;
                pf[hh].u[3] = lo ? ao1 : bo1;
            }

            // ---- O^T += V^T P^T, V-frag loads shared across heads
            __builtin_amdgcn_s_setprio(1);
#pragma unroll
            for (int ds = 0; ds < 8; ++ds) {
                int vrow = ds * 16 + l15;
                int vbyte = vrow * 64 + ((l4 * 16) ^ (((vrow >> 1) & 3) << 4));
                s8v bv = *reinterpret_cast<const s8v*>(Vc + vbyte);
                o[0][ds] = __builtin_amdgcn_mfma_f32_16x16x32_bf16(
                    bv, pf[0].v, o[0][ds], 0, 0, 0);
                o[1][ds] = __builtin_amdgcn_mfma_f32_16x16x32_bf16(
                    bv, pf[1].v, o[1][ds], 0, 0, 0);
            }
            __builtin_amdgcn_s_setprio(0);
        }

        // ---- tile end: counted wait (T4) — tile t+2's loads stay in flight
        if (t + 2 < NT) {
            asm volatile("s_waitcnt vmcnt(4) lgkmcnt(0)" ::: "memory");
        } else {
            asm volatile("s_waitcnt vmcnt(0) lgkmcnt(0)" ::: "memory");
        }
        __builtin_amdgcn_s_barrier();
        __builtin_amdgcn_sched_barrier(0);
        cur = (cur == 2) ? 0 : cur + 1;
    }

    // ---- epilogue per head: reduce l, normalize, b64 stores
#pragma unroll
    for (int hh = 0; hh < 2; ++hh) {
        float lv = l[hh];
        lv += __shfl_xor(lv, 16);
        lv += __shfl_xor(lv, 32);
        float inv = 1.0f / lv;
        size_t rowoff = ((size_t)b * T_SEQ + qrow0 + l15) * C_DIM
                        + (2 * hp + hh) * HD;
#pragma unroll
        for (int ds = 0; ds < 8; ++ds) {
            uint2 w;
            w.x = cvt2_bf16(o[hh][ds][0] * inv, o[hh][ds][1] * inv);
            w.y = cvt2_bf16(o[hh][ds][2] * inv, o[hh][ds][3] * inv);
            *reinterpret_cast<uint2*>(yattn + rowoff + ds * 16 + l4 * 4) = w;
        }
    }
}

// ---------------------------------------------------------------------------
extern "C" void kernel_launch(void* const* d_in, const int* in_sizes, int n_in,
                              void* d_out, int out_size, void* d_ws, size_t ws_size,
                              hipStream_t stream) {
    const float* x  = (const float*)d_in[0];
    // d_in[1] = attn_mask (fixed causal -1e9 triu; implemented analytically)
    const float* wq = (const float*)d_in[2];
    const float* wk = (const float*)d_in[3];
    const float* wv = (const float*)d_in[4];
    const float* wo = (const float*)d_in[5];

    char* ws = (char*)d_ws;
    size_t off = 0;
    auto alloc = [&](size_t bytes) -> void* {
        void* p = ws + off;
        off += (bytes + 255) & ~(size_t)255;
        return p;
    };
    unsigned short* xb    = (unsigned short*)alloc((size_t)4096 * 2048 * 2);
    unsigned short* wT    = (unsigned short*)alloc((size_t)2304 * 2048 * 2);
    unsigned short* woT   = (unsigned short*)alloc((size_t)2048 * 2048 * 2);
    float*          qkvKV = (float*)alloc((size_t)4096 * 256 * 4);
    float*          cosT  = (float*)alloc((size_t)2048 * 64 * 4);
    float*          sinT  = (float*)alloc((size_t)2048 * 64 * 4);
    float*          cosT2 = (float*)alloc((size_t)64 * 2048 * 4);
    float*          sinT2 = (float*)alloc((size_t)64 * 2048 * 4);
    unsigned short* qB    = (unsigned short*)alloc((size_t)2 * 16 * 2048 * 128 * 2);
    unsigned short* kB    = (unsigned short*)alloc((size_t)2 * 2048 * 128 * 2);
    unsigned short* vT    = (unsigned short*)alloc((size_t)2 * 128 * 2048 * 2);
    unsigned short* yattn = (unsigned short*)alloc((size_t)4096 * 2048 * 2);

    float* y_out = (float*)d_out;
    float* kexp  = y_out + (size_t)2 * 2048 * 2048;
    float* vexp  = kexp + (size_t)2 * 16 * 2048 * 128;

    k_prep<<<4736, 256, 0, stream>>>(x, xb, cosT, sinT, cosT2, sinT2,
                                     wq, wk, wv, wo, wT, woT);
    k_gemm_qkv<<<576, 256, 0, stream>>>(xb, wT, cosT2, sinT2, qB, qkvKV);
    k_kv_transform<<<4096, 192, 0, stream>>>(qkvKV, cosT, sinT, kB, vT, kexp, vexp);
    k_flash_attn<<<512, 256, 0, stream>>>(qB, kB, vT, yattn);
    k_gemm_bt<<<512, 256, 0, stream>>>(
        yattn, woT, y_out, 4096, 2048, 2048, 2048, 16);
}

// Round 18
// 229.366 us; speedup vs baseline: 1.0991x; 1.0991x over previous
//
#include <hip/hip_runtime.h>
#include <hip/hip_bf16.h>
#include <cstdint>
#include <cstddef>

#define B_SZ   2
#define T_SEQ  2048
#define C_DIM  2048
#define NH     16
#define HD     128

typedef __attribute__((ext_vector_type(8))) short s8v;      // 8 bf16
typedef __attribute__((ext_vector_type(4))) float f32x4;

typedef __attribute__((address_space(3))) char lds_char;
typedef __attribute__((address_space(1))) const char glob_char;

// softmax runs in exp2 domain: q pre-scale folds 1/sqrt(HD) * log2(e)
#define QSCALE 0.12751887f   // 0.088388348 * 1.4426950

__device__ __forceinline__ unsigned short f2bf(float f) {
    union { float f; uint32_t i; } v; v.f = f;
    uint32_t r = (v.i + 0x7FFFu + ((v.i >> 16) & 1u)) >> 16;
    return (unsigned short)r;
}

// packed pair: lo = bf16(a), hi = bf16(b)
__device__ __forceinline__ unsigned int cvt2_bf16(float a, float b) {
    unsigned int w;
    asm("v_cvt_pk_bf16_f32 %0, %1, %2" : "=v"(w) : "v"(a), "v"(b));
    return w;
}

// -------------------------------------------------------------- fused prep
__global__ __launch_bounds__(256) void k_prep(
        const float* __restrict__ x, unsigned short* __restrict__ xb,
        float* __restrict__ cosT, float* __restrict__ sinT,
        float* __restrict__ cosT2, float* __restrict__ sinT2,
        const float* __restrict__ wq, const float* __restrict__ wk,
        const float* __restrict__ wv, const float* __restrict__ wo,
        unsigned short* __restrict__ wT, unsigned short* __restrict__ woT) {
    __shared__ unsigned short tile[64][66];
    int blk = blockIdx.x;
    int tid = threadIdx.x;

    if (blk < 2048) {
        int i = blk * 256 + tid;
        const int n4 = 4096 * 2048 / 4;
        const int stride = 2048 * 256;
        for (; i < n4; i += stride) {
            float4 v = reinterpret_cast<const float4*>(x)[i];
            ushort4 o;
            o.x = f2bf(v.x); o.y = f2bf(v.y); o.z = f2bf(v.z); o.w = f2bf(v.w);
            reinterpret_cast<ushort4*>(xb)[i] = o;
        }
        return;
    }
    blk -= 2048;
    if (blk < 512) {
        int idx = blk * 256 + tid;            // T*64
        int t = idx >> 6, i = idx & 63;
        float inv = powf(10000.0f, -(float)i / 64.0f);
        float ang = (float)t * inv;
        float c = cosf(ang), s = sinf(ang);
        cosT[idx] = c;  sinT[idx] = s;
        cosT2[i * T_SEQ + t] = c;  sinT2[i * T_SEQ + t] = s;
        return;
    }
    blk -= 512;

    const float* in; unsigned short* out; int C, ldo, bx, by;
    if (blk < 1024) {
        in = wq; out = wT; C = 2048; ldo = 2048;
        bx = blk & 31; by = blk >> 5;
    } else if (blk < 1088) {
        int l = blk - 1024;
        in = wk; out = wT + (size_t)2048 * 2048; C = 128; ldo = 2048;
        bx = l & 1; by = l >> 1;
    } else if (blk < 1152) {
        int l = blk - 1088;
        in = wv; out = wT + (size_t)2176 * 2048; C = 128; ldo = 2048;
        bx = l & 1; by = l >> 1;
    } else {
        int l = blk - 1152;
        in = wo; out = woT; C = 2048; ldo = 2048;
        bx = l & 31; by = l >> 5;
    }
    int x0 = bx * 64, y0 = by * 64;
    int tx = tid & 63, ty = tid >> 6;
#pragma unroll
    for (int j = 0; j < 16; ++j) {
        int r = y0 + ty + j * 4;
        tile[ty + j * 4][tx] = f2bf(in[(size_t)r * C + x0 + tx]);
    }
    __syncthreads();
#pragma unroll
    for (int j = 0; j < 16; ++j) {
        int orow = x0 + ty + j * 4;
        out[(size_t)orow * ldo + y0 + tx] = tile[tx][ty + j * 4];
    }
}

// ----------------------------------------------------------------- GEMM (BT)
#define BM 128
#define BN 128
#define BK 64

__global__ __launch_bounds__(256) void k_gemm_bt(
        const unsigned short* __restrict__ A,
        const unsigned short* __restrict__ Bt,
        float* __restrict__ C, int M, int N, int K, int ldc, int gx) {
    __shared__ char smem[BM * BK * 2 + BN * BK * 2];   // 16KB A + 16KB B
    char* As = smem;
    char* Bs = smem + BM * BK * 2;
    int tid = threadIdx.x, lane = tid & 63, wid = tid >> 6;
    int nwg = gridDim.x, cpx = nwg >> 3;
    int orig = blockIdx.x;
    int wg = (orig & 7) * cpx + (orig >> 3);   // bijective: nwg % 8 == 0
    int bx = wg % gx, by = wg / gx;
    int m0 = by * BM, n0 = bx * BN;
    int wr = wid >> 1, wc = wid & 1;

    f32x4 acc[4][4] = {};

    int srow = wid * 32 + (lane >> 3);
    int cp = lane & 7;

    for (int k0 = 0; k0 < K; k0 += BK) {
#pragma unroll
        for (int i = 0; i < 4; ++i) {
            int row = srow + i * 8;
            int c = cp ^ (row & 7);
            const unsigned short* ga = A + (size_t)(m0 + row) * K + k0 + c * 8;
            const unsigned short* gb = Bt + (size_t)(n0 + row) * K + k0 + c * 8;
            __builtin_amdgcn_global_load_lds((glob_char*)ga,
                (lds_char*)(As + wid * 4096 + i * 1024), 16, 0, 0);
            __builtin_amdgcn_global_load_lds((glob_char*)gb,
                (lds_char*)(Bs + wid * 4096 + i * 1024), 16, 0, 0);
        }
        __syncthreads();

#pragma unroll
        for (int kc = 0; kc < 2; ++kc) {
            s8v af[4], bfr[4];
#pragma unroll
            for (int mi = 0; mi < 4; ++mi) {
                int row = wr * 64 + mi * 16 + (lane & 15);
                int slot = (kc * 4 + (lane >> 4)) ^ (row & 7);
                af[mi] = *reinterpret_cast<const s8v*>(As + row * 128 + slot * 16);
            }
#pragma unroll
            for (int ni = 0; ni < 4; ++ni) {
                int row = wc * 64 + ni * 16 + (lane & 15);
                int slot = (kc * 4 + (lane >> 4)) ^ (row & 7);
                bfr[ni] = *reinterpret_cast<const s8v*>(Bs + row * 128 + slot * 16);
            }
#pragma unroll
            for (int mi = 0; mi < 4; ++mi)
#pragma unroll
                for (int ni = 0; ni < 4; ++ni)
                    acc[mi][ni] = __builtin_amdgcn_mfma_f32_16x16x32_bf16(
                        af[mi], bfr[ni], acc[mi][ni], 0, 0, 0);
        }
        __syncthreads();
    }

#pragma unroll
    for (int mi = 0; mi < 4; ++mi) {
        int row = m0 + wr * 64 + mi * 16 + ((lane >> 4) << 2);
#pragma unroll
        for (int ni = 0; ni < 4; ++ni) {
            int col = n0 + wc * 64 + ni * 16 + (lane & 15);
            float* cp2 = C + (size_t)row * ldc + col;
#pragma unroll
            for (int r = 0; r < 4; ++r)
                cp2[(size_t)r * ldc] = acc[mi][ni][r];
        }
    }
}

// ------------------------- QKV GEMM, 2x2 wave split + LDS RoPE exchange
__global__ __launch_bounds__(256) void k_gemm_qkv(
        const unsigned short* __restrict__ A,
        const unsigned short* __restrict__ Bt,
        const float* __restrict__ cosT2,
        const float* __restrict__ sinT2,
        unsigned short* __restrict__ qB,
        float* __restrict__ qkvKV) {
    const int GX = 18, K = 2048;
    __shared__ char smem[34816];   // 32KB staging; 34KB epilogue exchange
    char* As = smem;
    char* Bs = smem + BM * BK * 2;
    int tid = threadIdx.x, lane = tid & 63, wid = tid >> 6;
    int nwg = gridDim.x, cpx = nwg >> 3;       // 576 -> 72
    int orig = blockIdx.x;
    int wg = (orig & 7) * cpx + (orig >> 3);
    int bx = wg % GX, by = wg / GX;
    int m0 = by * BM, n0 = bx * BN;
    int l15 = lane & 15, l4 = lane >> 4;
    int wr = wid >> 1, wc = wid & 1;

    f32x4 acc[4][4] = {};

    int srow = wid * 32 + (lane >> 3);
    int cp = lane & 7;

    for (int k0 = 0; k0 < K; k0 += BK) {
#pragma unroll
        for (int i = 0; i < 4; ++i) {
            int row = srow + i * 8;
            int c = cp ^ (row & 7);
            const unsigned short* ga = A + (size_t)(m0 + row) * K + k0 + c * 8;
            const unsigned short* gb = Bt + (size_t)(n0 + row) * K + k0 + c * 8;
            __builtin_amdgcn_global_load_lds((glob_char*)ga,
                (lds_char*)(As + wid * 4096 + i * 1024), 16, 0, 0);
            __builtin_amdgcn_global_load_lds((glob_char*)gb,
                (lds_char*)(Bs + wid * 4096 + i * 1024), 16, 0, 0);
        }
        __syncthreads();

#pragma unroll
        for (int kc = 0; kc < 2; ++kc) {
            s8v af[4], bfr[4];
#pragma unroll
            for (int mi = 0; mi < 4; ++mi) {
                int row = wr * 64 + mi * 16 + l15;
                int slot = (kc * 4 + l4) ^ (row & 7);
                af[mi] = *reinterpret_cast<const s8v*>(As + row * 128 + slot * 16);
            }
#pragma unroll
            for (int ni = 0; ni < 4; ++ni) {
                int row = wc * 64 + ni * 16 + l15;
                int slot = (kc * 4 + l4) ^ (row & 7);
                bfr[ni] = *reinterpret_cast<const s8v*>(Bs + row * 128 + slot * 16);
            }
#pragma unroll
            for (int mi = 0; mi < 4; ++mi)
#pragma unroll
                for (int ni = 0; ni < 4; ++ni)
                    acc[mi][ni] = __builtin_amdgcn_mfma_f32_16x16x32_bf16(
                        af[mi], bfr[ni], acc[mi][ni], 0, 0, 0);
        }
        __syncthreads();
    }

    if (bx < 16) {
        // ---- RoPE epilogue with cross-wc LDS exchange
        float* xch = reinterpret_cast<float*>(smem);
        if (wc == 1) {
            float* base = xch + ((size_t)wr * 64 + lane) * 68;
#pragma unroll
            for (int mi = 0; mi < 4; ++mi)
#pragma unroll
                for (int ni = 0; ni < 4; ++ni)
                    *reinterpret_cast<f32x4*>(base + mi * 16 + ni * 4) =
                        acc[mi][ni];
        }
        __syncthreads();
        if (wc == 0) {
            int b = m0 >> 11, h = bx;
            const float* pbase = xch + ((size_t)wr * 64 + lane) * 68;
#pragma unroll
            for (int mi = 0; mi < 4; ++mi) {
                int t0 = ((m0 & (T_SEQ - 1)) + wr * 64 + mi * 16 + l4 * 4);
#pragma unroll
                for (int ni = 0; ni < 4; ++ni) {
                    int d = ni * 16 + l15;          // d in [0,64)
                    float4 c4 = *reinterpret_cast<const float4*>(
                        cosT2 + (size_t)d * T_SEQ + t0);
                    float4 s4 = *reinterpret_cast<const float4*>(
                        sinT2 + (size_t)d * T_SEQ + t0);
                    f32x4 px = *reinterpret_cast<const f32x4*>(
                        pbase + mi * 16 + ni * 4);
#pragma unroll
                    for (int r = 0; r < 4; ++r) {
                        float x1 = acc[mi][ni][r];
                        float x2 = px[r];
                        float cc = (&c4.x)[r], ss = (&s4.x)[r];
                        float o1 = (x1 * cc - x2 * ss) * QSCALE;
                        float o2 = (x2 * cc + x1 * ss) * QSCALE;
                        size_t qoff = ((size_t)(b * NH + h) * T_SEQ + t0 + r)
                                      * HD + 2 * d;
                        *reinterpret_cast<unsigned int*>(qB + qoff) =
                            cvt2_bf16(o1, o2);
                    }
                }
            }
        }
    } else {
        int colb = (bx - 16) * 128;
#pragma unroll
        for (int mi = 0; mi < 4; ++mi) {
            int row = m0 + wr * 64 + mi * 16 + l4 * 4;
#pragma unroll
            for (int ni = 0; ni < 4; ++ni) {
                int col = colb + wc * 64 + ni * 16 + l15;
                float* cp2 = qkvKV + (size_t)row * 256 + col;
#pragma unroll
                for (int r = 0; r < 4; ++r)
                    cp2[(size_t)r * 256] = acc[mi][ni][r];
            }
        }
    }
}

// -------------------------------------------- slim k/v transform + broadcast
__global__ __launch_bounds__(192) void k_kv_transform(
                               const float* __restrict__ qkvKV,
                               const float* __restrict__ cosT,
                               const float* __restrict__ sinT,
                               unsigned short* __restrict__ kB,
                               unsigned short* __restrict__ vT,
                               float* __restrict__ kexp,
                               float* __restrict__ vexp) {
    int bt = blockIdx.x;
    int b = bt >> 11, t = bt & 2047;
    int tid = threadIdx.x;
    const float* base = qkvKV + (size_t)bt * 256;

    if (tid < 64) {
        int d = tid;
        float c = cosT[t * 64 + d], s = sinT[t * 64 + d];
        float k1 = base[d], k2 = base[d + 64];
        float o1 = k1 * c - k2 * s;
        float o2 = k2 * c + k1 * s;
        size_t koff = ((size_t)b * T_SEQ + t) * HD + 2 * d;   // interleaved
        *reinterpret_cast<unsigned int*>(kB + koff) = cvt2_bf16(o1, o2);
#pragma unroll
        for (int h = 0; h < NH; ++h) {
            size_t eoff = ((size_t)(b * NH + h) * T_SEQ + t) * HD + d;
            kexp[eoff] = o1;          // canonical layout (required output)
            kexp[eoff + 64] = o2;
        }
    } else {
        int d = tid - 64;             // 0..127
        float v = base[128 + d];
        vT[((size_t)b * HD + d) * T_SEQ + t] = f2bf(v);
#pragma unroll
        for (int h = 0; h < NH; ++h)
            vexp[((size_t)(b * NH + h) * T_SEQ + t) * HD + d] = v;
    }
}

// ---------------------------------------------------------- flash attention
// v13 EXACT REVERT (R16 config, ~89-91us, occupancy ~24%): swapped-QK 16x16,
// in-lane softmax, in-reg P exchange, 3-buf counted vmcnt, 1024 blocks
// (4 blocks/CU). R17's 2-head variant halved the grid to 2 blocks/CU and
// regressed 17% — attn TLP (>=4 blocks/CU) outweighs work-efficiency.
__global__ __launch_bounds__(256, 3) void k_flash_attn(
        const unsigned short* __restrict__ qB,
        const unsigned short* __restrict__ kB,
        const unsigned short* __restrict__ vT,
        unsigned short* __restrict__ yattn) {
    __shared__ char smem[49152];   // 3 x (K 8K | V 8K)
    int tid = threadIdx.x, lane = tid & 63, wvid = tid >> 6;
    int l15 = lane & 15, l4 = lane >> 4;
    int blk = blockIdx.x;
    int bh = blk & 31;
    int b = bh >> 4, h = bh & 15;
    int g = blk >> 5;                  // 0..31
    int a = g & 7, qq = g >> 3;
    int u = (qq == 0) ? (31 - a) : (qq == 1) ? (16 + a)
          : (qq == 2) ? (15 - a) : a;          // CU-balanced, heavy first
    int qrow0 = u * 64 + wvid * 16;

    const unsigned short* kbB   = kB + (size_t)b * T_SEQ * HD;
    const unsigned short* vbase = vT + (size_t)b * HD * T_SEQ;

    const unsigned short* qbase =
        qB + ((size_t)(b * NH + h) * T_SEQ + qrow0) * HD;
    s8v aq[4];
#pragma unroll
    for (int kc = 0; kc < 4; ++kc)
        aq[kc] = *reinterpret_cast<const s8v*>(
            qbase + (size_t)l15 * HD + kc * 32 + l4 * 8);

    float m = -3e38f, l = 0.f;
    f32x4 o[8] = {};   // O^T: col=q=l15, row-slot: d = ds*16 + l4*4 + r

    int NT = 2 * u + 2;   // 32-wide kv tiles (NT >= 2 always)

    auto stage = [&](int buf, int t) {
        int kv0 = t * 32;
        char* kdst = smem + buf * 16384;
        char* vdst = smem + buf * 16384 + 8192;
#pragma unroll
        for (int j = 0; j < 2; ++j) {
            int n = j * 256 + tid;            // K chunk 0..511
            int row = n >> 4, ch = n & 15;
            const unsigned short* src =
                kbB + (size_t)(kv0 + row) * HD + (ch ^ (row & 7)) * 8;
            __builtin_amdgcn_global_load_lds((glob_char*)src,
                (lds_char*)(kdst + j * 4096 + wvid * 1024), 16, 0, 0);
        }
#pragma unroll
        for (int j = 0; j < 2; ++j) {
            int n = j * 256 + tid;            // V chunk 0..511
            int row = n >> 2, ch = n & 3;     // 4 chunks per 64B row
            const unsigned short* src =
                vbase + (size_t)row * T_SEQ + kv0 + (ch ^ ((row >> 1) & 3)) * 8;
            __builtin_amdgcn_global_load_lds((glob_char*)src,
                (lds_char*)(vdst + j * 4096 + wvid * 1024), 16, 0, 0);
        }
    };

    stage(0, 0);
    stage(1, 1);
    asm volatile("s_waitcnt vmcnt(4)" ::: "memory");
    __builtin_amdgcn_s_barrier();
    __builtin_amdgcn_sched_barrier(0);

    int cur = 0;
    for (int t = 0; t < NT; ++t) {
        int nb = cur + 2; if (nb >= 3) nb -= 3;
        if (t + 2 < NT) stage(nb, t + 2);     // 2-deep prefetch, issued first
        int kv0 = t * 32;
        const char* Kc = smem + cur * 16384;
        const char* Vc = smem + cur * 16384 + 8192;
        int act = (kv0 <= qrow0 + 15);        // any unmasked row for wave?

        if (act) {
            // ---- S^T = K Q^T (exp2-domain): C[col=q=l15][row=l4*4+r=kv-slot]
            f32x4 sfr[2] = {};
            __builtin_amdgcn_s_setprio(1);
#pragma unroll
            for (int kc = 0; kc < 4; ++kc) {
                s8v kf[2];
#pragma unroll
                for (int n = 0; n < 2; ++n) {
                    int row = n * 16 + l15;
                    int byte = row * 256 +
                        ((kc * 64 + l4 * 16) ^ ((row & 7) << 4));
                    kf[n] = *reinterpret_cast<const s8v*>(Kc + byte);
                }
#pragma unroll
                for (int n = 0; n < 2; ++n)
                    sfr[n] = __builtin_amdgcn_mfma_f32_16x16x32_bf16(
                        kf[n], aq[kc], sfr[n], 0, 0, 0);   // SWAPPED
            }
            __builtin_amdgcn_s_setprio(0);

            // ---- causal mask: kv = kv0 + n*16 + l4*4 + r vs q = qrow0 + l15
            if (kv0 + 31 > qrow0) {
                int qa = qrow0 + l15;
#pragma unroll
                for (int n = 0; n < 2; ++n)
#pragma unroll
                    for (int r = 0; r < 4; ++r) {
                        int kv = kv0 + n * 16 + l4 * 4 + r;
                        if (kv > qa) sfr[n][r] = -1e9f;
                    }
            }

            // ---- online softmax: in-lane over 8 + cross-l4 (2 shfl_xor)
            float pm = sfr[0][0];
#pragma unroll
            for (int r = 1; r < 4; ++r) pm = fmaxf(pm, sfr[0][r]);
#pragma unroll
            for (int r = 0; r < 4; ++r) pm = fmaxf(pm, sfr[1][r]);
            pm = fmaxf(pm, __shfl_xor(pm, 16));
            pm = fmaxf(pm, __shfl_xor(pm, 32));
            if (!__all(pm <= m + 8.0f)) {       // defer-max (T13)
                float mn = fmaxf(m, pm);
                float al = exp2f(m - mn);
                l *= al;
#pragma unroll
                for (int ds = 0; ds < 8; ++ds)
#pragma unroll
                    for (int r = 0; r < 4; ++r) o[ds][r] *= al;
                m = mn;
            }
#pragma unroll
            for (int n = 0; n < 2; ++n)
#pragma unroll
                for (int r = 0; r < 4; ++r) {
                    float p = exp2f(sfr[n][r] - m);
                    sfr[n][r] = p;
                    l += p;                     // per-lane partial
                }

            // ---- P^T B-frag in registers: lane l4 holds kv-quads {l4, l4+4}
            unsigned int a0 = cvt2_bf16(sfr[0][0], sfr[0][1]);
            unsigned int a1 = cvt2_bf16(sfr[0][2], sfr[0][3]);
            unsigned int b0 = cvt2_bf16(sfr[1][0], sfr[1][1]);
            unsigned int b1 = cvt2_bf16(sfr[1][2], sfr[1][3]);
            int srcE = (lane & 15) | ((lane & 16) << 1);
            int srcO = srcE + 16;
            unsigned int ae0 = __shfl(a0, srcE), ae1 = __shfl(a1, srcE);
            unsigned int be0 = __shfl(b0, srcE), be1 = __shfl(b1, srcE);
            unsigned int ao0 = __shfl(a0, srcO), ao1 = __shfl(a1, srcO);
            unsigned int bo0 = __shfl(b0, srcO), bo1 = __shfl(b1, srcO);
            bool lo = (lane & 32) == 0;
            union { unsigned int u[4]; s8v v; } pf;
            pf.u[0] = lo ? ae0 : be0;
            pf.u[1] = lo ? ae1 : be1;
            pf.u[2] = lo ? ao0 : bo0;
            pf.u[3] = lo ? ao1 : bo1;

            // ---- O^T += V^T P^T  (A=V-frag unchanged, B=pf)
            __builtin_amdgcn_s_setprio(1);
#pragma unroll
            for (int ds = 0; ds < 8; ++ds) {
                int vrow = ds * 16 + l15;
                int vbyte = vrow * 64 + ((l4 * 16) ^ (((vrow >> 1) & 3) << 4));
                s8v bv = *reinterpret_cast<const s8v*>(Vc + vbyte);
                o[ds] = __builtin_amdgcn_mfma_f32_16x16x32_bf16(
                    bv, pf.v, o[ds], 0, 0, 0);
            }
            __builtin_amdgcn_s_setprio(0);
        }

        // ---- tile end: counted wait (T4) — tile t+2's loads stay in flight
        if (t + 2 < NT) {
            asm volatile("s_waitcnt vmcnt(4) lgkmcnt(0)" ::: "memory");
        } else {
            asm volatile("s_waitcnt vmcnt(0) lgkmcnt(0)" ::: "memory");
        }
        __builtin_amdgcn_s_barrier();
        __builtin_amdgcn_sched_barrier(0);
        cur = (cur == 2) ? 0 : cur + 1;
    }

    // ---- epilogue: reduce l across l4 groups, normalize, b64 stores
    l += __shfl_xor(l, 16);
    l += __shfl_xor(l, 32);
    float inv = 1.0f / l;
    size_t rowoff = ((size_t)b * T_SEQ + qrow0 + l15) * C_DIM + h * HD;
#pragma unroll
    for (int ds = 0; ds < 8; ++ds) {
        uint2 w;
        w.x = cvt2_bf16(o[ds][0] * inv, o[ds][1] * inv);
        w.y = cvt2_bf16(o[ds][2] * inv, o[ds][3] * inv);
        *reinterpret_cast<uint2*>(yattn + rowoff + ds * 16 + l4 * 4) = w;
    }
}

// ---------------------------------------------------------------------------
extern "C" void kernel_launch(void* const* d_in, const int* in_sizes, int n_in,
                              void* d_out, int out_size, void* d_ws, size_t ws_size,
                              hipStream_t stream) {
    const float* x  = (const float*)d_in[0];
    // d_in[1] = attn_mask (fixed causal -1e9 triu; implemented analytically)
    const float* wq = (const float*)d_in[2];
    const float* wk = (const float*)d_in[3];
    const float* wv = (const float*)d_in[4];
    const float* wo = (const float*)d_in[5];

    char* ws = (char*)d_ws;
    size_t off = 0;
    auto alloc = [&](size_t bytes) -> void* {
        void* p = ws + off;
        off += (bytes + 255) & ~(size_t)255;
        return p;
    };
    unsigned short* xb    = (unsigned short*)alloc((size_t)4096 * 2048 * 2);
    unsigned short* wT    = (unsigned short*)alloc((size_t)2304 * 2048 * 2);
    unsigned short* woT   = (unsigned short*)alloc((size_t)2048 * 2048 * 2);
    float*          qkvKV = (float*)alloc((size_t)4096 * 256 * 4);
    float*          cosT  = (float*)alloc((size_t)2048 * 64 * 4);
    float*          sinT  = (float*)alloc((size_t)2048 * 64 * 4);
    float*          cosT2 = (float*)alloc((size_t)64 * 2048 * 4);
    float*          sinT2 = (float*)alloc((size_t)64 * 2048 * 4);
    unsigned short* qB    = (unsigned short*)alloc((size_t)2 * 16 * 2048 * 128 * 2);
    unsigned short* kB    = (unsigned short*)alloc((size_t)2 * 2048 * 128 * 2);
    unsigned short* vT    = (unsigned short*)alloc((size_t)2 * 128 * 2048 * 2);
    unsigned short* yattn = (unsigned short*)alloc((size_t)4096 * 2048 * 2);

    float* y_out = (float*)d_out;
    float* kexp  = y_out + (size_t)2 * 2048 * 2048;
    float* vexp  = kexp + (size_t)2 * 16 * 2048 * 128;

    k_prep<<<4736, 256, 0, stream>>>(x, xb, cosT, sinT, cosT2, sinT2,
                                     wq, wk, wv, wo, wT, woT);
    k_gemm_qkv<<<576, 256, 0, stream>>>(xb, wT, cosT2, sinT2, qB, qkvKV);
    k_kv_transform<<<4096, 192, 0, stream>>>(qkvKV, cosT, sinT, kB, vT, kexp, vexp);
    k_flash_attn<<<1024, 256, 0, stream>>>(qB, kB, vT, yattn);
    k_gemm_bt<<<512, 256, 0, stream>>>(
        yattn, woT, y_out, 4096, 2048, 2048, 2048, 16);
}